// Round 9
// baseline (246.529 us; speedup 1.0000x reference)
//
#include <hip/hip_runtime.h>
#include <hip/hip_bf16.h>

#define N_ROWS 4096
#define TWO_N  8192
#define ZDIM   256
#define INV_T  (1.0f/0.07f)
// exp((s-1)/T) = exp2((s-1) * INV_T * log2(e))
#define EXP_SCALE (INV_T * 1.44269504088896340736f)
// 64-bit magic barrier tokens: collision with poison (0xAA..) or fresh-alloc garbage is
// ~2^-64/slot; stale MAGIC from a prior pass makes barriers pass-through (never deadlock).
#define MAGIC1 0x5B17C0DEF00D0001ULL
#define MAGIC2 0x5B17C0DEF00D0002ULL

typedef __attribute__((ext_vector_type(4))) float f32x4;

__device__ __forceinline__ void async_load16(const void* g, void* lds_uniform_base) {
  // HW computes LDS dest = (wave-uniform base) + lane*16; pass base WITHOUT lane term.
  __builtin_amdgcn_global_load_lds(
      (const __attribute__((address_space(1))) void*)g,
      (__attribute__((address_space(3))) void*)lds_uniform_base, 16, 0, 0);
}

// float -> OCP e4m3fn, round-to-nearest-even. Inputs here are |x| <= 1.
__device__ __forceinline__ unsigned char f32_to_e4m3(float x) {
  unsigned int u = __float_as_uint(x);
  const unsigned int s = u >> 31;
  unsigned int a = u & 0x7FFFFFFFu;
  if (a > 0x43E00000u) a = 0x43E00000u;
  const float f = __uint_as_float(a);
  unsigned int out;
  if (a < (121u << 23)) {                        // |x| < 2^-6: subnormal, step 2^-9
    const int m = (int)rintf(f * 512.0f);
    out = (unsigned int)m;
  } else {
    const unsigned int r = a + 0x7FFFFu + ((a >> 20) & 1u);  // RNE to 3 mantissa bits
    const unsigned int e8 = (r >> 23) - 120u;
    out = (e8 << 3) | ((r >> 20) & 7u);
  }
  return (unsigned char)(out | (s << 7));
}

// ---------------- Fused kernel: normalize -> grid barrier -> simsum -> reduce -----------
// 512 blocks = EXACTLY 2/CU x 256 CU residency capacity (66 KB LDS, 132 VGPR <= 256/wave
// at 2 waves/SIMD), so flag-based grid barriers are deadlock-free: all blocks resident.
// Phase 1: block bid normalizes rows [bid*8,+8) of z1 AND z2 (4096 total rows — R8 bug
// was 16/block = 8192 -> OOB page fault).
// Barrier 1 (flags1). Phase 2: triangular pipelined fp8 simsum (R7 structure). Publish +
// flags2. Phase 3: blocks bid<128 spin on flags2, each reduces 64 rows + 32 pos entries,
// one atomicAdd(out) per reducer.
__global__ __launch_bounds__(256, 2) void fused_kernel(
    const float* __restrict__ z1, const float* __restrict__ z2,
    unsigned char* __restrict__ reps, float* __restrict__ pos,
    float* __restrict__ rowscratch,   // [64][8][128]
    float* __restrict__ colscratch,   // [64][32][128]
    unsigned long long* __restrict__ flags1,
    unsigned long long* __restrict__ flags2,
    float* __restrict__ out) {
  __shared__ __align__(16) unsigned char Alds[128 * 256];     // 32 KB
  __shared__ __align__(16) unsigned char Blds[2][128 * 128];  // 2 x 16 KB
  __shared__ float colred[2][256];                            // 2 KB  (total 66 KB)

  const int tid  = threadIdx.x;
  const int lane = tid & 63;
  const int wave = tid >> 6;
  const int wm = wave >> 1, wn = wave & 1;   // 2x2 wave grid
  const int quad = lane >> 4;                // 0..3
  const int l16  = lane & 15;
  const int itile = blockIdx.x;              // row tile 0..63
  const int chunk = blockIdx.y;              // distance chunk 0..7
  const int bid = chunk * 64 + itile;        // 0..511
  const int rowBase = itile * 128;
  const char* gbase = (const char*)reps;
  const bool diaghere = (chunk == 0);

  // ======== Phase 1: normalize rows [bid*8, +8), wave-per-row (512*8 = 4096 rows) ======
  #pragma unroll
  for (int it = 0; it < 2; ++it) {
    const int r = bid * 8 + it * 4 + wave;   // 0..4095 — each r covers z1[r] AND z2[r]
    const float4 a = ((const float4*)(z1 + (size_t)r * ZDIM))[lane];
    const float4 b = ((const float4*)(z2 + (size_t)r * ZDIM))[lane];
    float s1 = a.x*a.x + a.y*a.y + a.z*a.z + a.w*a.w;
    float s2 = b.x*b.x + b.y*b.y + b.z*b.z + b.w*b.w;
    float s3 = a.x*b.x + a.y*b.y + a.z*b.z + a.w*b.w;
    #pragma unroll
    for (int m = 1; m < 64; m <<= 1) {
      s1 += __shfl_xor(s1, m, 64);
      s2 += __shfl_xor(s2, m, 64);
      s3 += __shfl_xor(s3, m, 64);
    }
    const float inv1 = 1.0f / fmaxf(sqrtf(s1), 1e-12f);
    const float inv2 = 1.0f / fmaxf(sqrtf(s2), 1e-12f);
    uchar4 pa, pb;
    pa.x = f32_to_e4m3(a.x * inv1); pa.y = f32_to_e4m3(a.y * inv1);
    pa.z = f32_to_e4m3(a.z * inv1); pa.w = f32_to_e4m3(a.w * inv1);
    pb.x = f32_to_e4m3(b.x * inv2); pb.y = f32_to_e4m3(b.y * inv2);
    pb.z = f32_to_e4m3(b.z * inv2); pb.w = f32_to_e4m3(b.w * inv2);
    ((uchar4*)(reps + (size_t)r * ZDIM))[lane] = pa;
    ((uchar4*)(reps + (size_t)(r + N_ROWS) * ZDIM))[lane] = pb;
    if (lane == 0) pos[r] = s3 * inv1 * inv2;
  }
  if (bid == 0 && tid == 0) out[0] = INV_T;  // overwrite poison; reducers add onto this

  // ======== Barrier 1: all 512 blocks ========
  __threadfence();    // release phase-1 stores to device scope
  __syncthreads();
  if (tid == 0)
    __hip_atomic_store(&flags1[bid], MAGIC1, __ATOMIC_RELEASE, __HIP_MEMORY_SCOPE_AGENT);
  for (int f = tid; f < 512; f += 256)
    while (__hip_atomic_load(&flags1[f], __ATOMIC_ACQUIRE,
                             __HIP_MEMORY_SCOPE_AGENT) != MAGIC1)
      __builtin_amdgcn_s_sleep(1);
  __threadfence();    // acquire: invalidate stale cache before reading other blocks' reps
  __syncthreads();

  // ======== Phase 2: triangular fp8 simsum, K=128 ping-pong pipeline (R7) ========
  {
    const int r0 = tid >> 4;
    const int src = (tid & 8) | ((tid ^ (tid >> 4)) & 7);      // XOR-low3 swizzle
    const char* g0 = gbase + (rowBase + r0) * ZDIM + src * 16;
    char* l0 = (char*)Alds + (wave << 10);
    #pragma unroll
    for (int p = 0; p < 8; ++p)
      async_load16(g0 + p * 16 * ZDIM, l0 + p * 4096);
  }

  int doff[4];
  int noff;
  if (diaghere) {
    doff[0] = 1; doff[1] = 2; doff[2] = 3; doff[3] = 32;
    noff = (itile < 32) ? 4 : 3;
  } else {
    doff[0] = chunk * 4; doff[1] = chunk * 4 + 1;
    doff[2] = chunk * 4 + 2; doff[3] = chunk * 4 + 3;
    noff = 4;
  }
  const int Q = noff * 2;   // chunk-steps: tile t = q>>1, k-half c = q&1

#define STAGE_B(q_) do {                                                        \
    const int t_ = (q_) >> 1, c_ = (q_) & 1;                                    \
    const int jt_ = (itile + doff[t_]) & 63;                                    \
    const int r0_ = tid >> 3;                                                   \
    const int src_ = (tid ^ (tid >> 3)) & 7;                                    \
    const char* g0_ = gbase + (jt_ * 128 + r0_) * ZDIM + c_ * 128 + src_ * 16;  \
    char* l0_ = (char*)Blds[c_] + (wave << 10);                                 \
    _Pragma("unroll")                                                           \
    for (int p_ = 0; p_ < 4; ++p_)                                              \
      async_load16(g0_ + p_ * 32 * ZDIM, l0_ + p_ * 4096);                      \
  } while (0)

  float rowpart[16];
  #pragma unroll
  for (int i = 0; i < 16; ++i) rowpart[i] = 0.0f;
  const f32x4 zero4 = {0.0f, 0.0f, 0.0f, 0.0f};

  if (diaghere) {
    __syncthreads();                  // drain A
    if (Q > 0) STAGE_B(0);            // covered by the diag compute below
    f32x4 acc[4][4];
    #pragma unroll
    for (int mi = 0; mi < 4; ++mi)
      #pragma unroll
      for (int ni = 0; ni < 4; ++ni) acc[mi][ni] = zero4;
    #pragma unroll
    for (int w = 0; w < 8; ++w) {
      const int o = w * 4 + quad;
      const int k16 = o >> 1, half = (o & 1) * 8;
      long afrag[4], bfrag[4];
      #pragma unroll
      for (int mi = 0; mi < 4; ++mi) {
        const int m = wm * 64 + mi * 16 + l16;
        const int sw = (k16 & 8) | ((k16 ^ m) & 7);
        afrag[mi] = *(const long*)((const char*)Alds + m * 256 + sw * 16 + half);
      }
      #pragma unroll
      for (int ni = 0; ni < 4; ++ni) {
        const int n = wn * 64 + ni * 16 + l16;
        const int sw = (k16 & 8) | ((k16 ^ n) & 7);
        bfrag[ni] = *(const long*)((const char*)Alds + n * 256 + sw * 16 + half);
      }
      #pragma unroll
      for (int mi = 0; mi < 4; ++mi)
        #pragma unroll
        for (int ni = 0; ni < 4; ++ni)
          acc[mi][ni] = __builtin_amdgcn_mfma_f32_16x16x32_fp8_fp8(
              afrag[mi], bfrag[ni], acc[mi][ni], 0, 0, 0);
    }
    #pragma unroll
    for (int mi = 0; mi < 4; ++mi)
      #pragma unroll
      for (int r = 0; r < 4; ++r) {
        const int grow = rowBase + wm * 64 + mi * 16 + quad * 4 + r;
        float s = 0.0f;
        #pragma unroll
        for (int ni = 0; ni < 4; ++ni) {
          const int gcol = rowBase + wn * 64 + ni * 16 + l16;
          const float e = exp2f((acc[mi][ni][r] - 1.0f) * EXP_SCALE);
          if (grow != gcol) s += e;
        }
        rowpart[mi * 4 + r] += s;
      }
    __syncthreads();                  // drain stage(0)
  } else {
    STAGE_B(0);
    __syncthreads();                  // drain A + stage(0)
  }

  f32x4 acc[4][4];
  for (int q = 0; q < Q; ++q) {
    if (q + 1 < Q) STAGE_B(q + 1);    // in flight during compute(q)
    const int t = q >> 1, c = q & 1;
    const int d = doff[t];
    const int jtile = (itile + d) & 63;

    if (c == 0) {
      #pragma unroll
      for (int mi = 0; mi < 4; ++mi)
        #pragma unroll
        for (int ni = 0; ni < 4; ++ni) acc[mi][ni] = zero4;
    }
    #pragma unroll
    for (int ws = 0; ws < 4; ++ws) {
      const int o  = c * 16 + ws * 4 + quad;
      const int k16 = o >> 1, half = (o & 1) * 8;
      const int ol = ws * 4 + quad;
      const int k16l = ol >> 1, halfl = (ol & 1) * 8;
      long afrag[4], bfrag[4];
      #pragma unroll
      for (int mi = 0; mi < 4; ++mi) {
        const int m = wm * 64 + mi * 16 + l16;
        const int sw = (k16 & 8) | ((k16 ^ m) & 7);
        afrag[mi] = *(const long*)((const char*)Alds + m * 256 + sw * 16 + half);
      }
      #pragma unroll
      for (int ni = 0; ni < 4; ++ni) {
        const int n = wn * 64 + ni * 16 + l16;
        const int sw = (k16l ^ n) & 7;
        bfrag[ni] = *(const long*)((const char*)Blds[c] + n * 128 + sw * 16 + halfl);
      }
      #pragma unroll
      for (int mi = 0; mi < 4; ++mi)
        #pragma unroll
        for (int ni = 0; ni < 4; ++ni)
          acc[mi][ni] = __builtin_amdgcn_mfma_f32_16x16x32_fp8_fp8(
              afrag[mi], bfrag[ni], acc[mi][ni], 0, 0, 0);
    }

    if (c == 1) {
      float colpart[4] = {0.0f, 0.0f, 0.0f, 0.0f};
      #pragma unroll
      for (int mi = 0; mi < 4; ++mi)
        #pragma unroll
        for (int r = 0; r < 4; ++r) {
          float s = 0.0f;
          #pragma unroll
          for (int ni = 0; ni < 4; ++ni) {
            const float e = exp2f((acc[mi][ni][r] - 1.0f) * EXP_SCALE);
            s += e;
            colpart[ni] += e;
          }
          rowpart[mi * 4 + r] += s;
        }
      #pragma unroll
      for (int ni = 0; ni < 4; ++ni) {
        float v = colpart[ni];
        v += __shfl_xor(v, 16, 64);
        v += __shfl_xor(v, 32, 64);
        if (quad == 0) colred[t & 1][wm * 128 + wn * 64 + ni * 16 + l16] = v;
      }
      __syncthreads();   // drains stage(q+1); colred visible; buffers free
      if (tid < 128)
        colscratch[(jtile * 32 + (d - 1)) * 128 + tid] =
            colred[t & 1][tid] + colred[t & 1][128 + tid];
    } else {
      __syncthreads();   // drains stage(q+1)
    }
  }
#undef STAGE_B

  // row partials: shfl over 16 col-lanes, merge wn-halves via LDS (same rows!)
  #pragma unroll
  for (int i = 0; i < 16; ++i) {
    float v = rowpart[i];
    v += __shfl_xor(v, 1, 64);
    v += __shfl_xor(v, 2, 64);
    v += __shfl_xor(v, 4, 64);
    v += __shfl_xor(v, 8, 64);
    rowpart[i] = v;
  }
  __syncthreads();
  if (l16 == 0) {
    #pragma unroll
    for (int mi = 0; mi < 4; ++mi)
      #pragma unroll
      for (int r = 0; r < 4; ++r)
        colred[0][wn * 128 + wm * 64 + mi * 16 + quad * 4 + r] = rowpart[mi * 4 + r];
  }
  __syncthreads();
  if (tid < 128)
    rowscratch[(itile * 8 + chunk) * 128 + tid] = colred[0][tid] + colred[0][128 + tid];

  // ======== Publish + Barrier 2 ========
  __threadfence();    // release row/col scratch stores
  __syncthreads();
  if (tid == 0)
    __hip_atomic_store(&flags2[bid], MAGIC2, __ATOMIC_RELEASE, __HIP_MEMORY_SCOPE_AGENT);

  // ======== Phase 3: 128 reducer blocks (rows [bid*64,+64), pos [bid*32,+32)) ========
  if (bid >= 128) return;
  for (int f = tid; f < 512; f += 256)
    while (__hip_atomic_load(&flags2[f], __ATOMIC_ACQUIRE,
                             __HIP_MEMORY_SCOPE_AGENT) != MAGIC2)
      __builtin_amdgcn_s_sleep(1);
  __threadfence();    // acquire: invalidate before reading other blocks' scratch
  __syncthreads();

  const int jt = bid >> 1;           // tile of our 64 rows
  const int rb = (bid & 1) * 64;     // row offset within tile
  float s = 0.0f;
  if (wave == 0) {
    #pragma unroll
    for (int c = 0; c < 8; ++c) s += rowscratch[(jt * 8 + c) * 128 + rb + lane];
  } else {
    const int ns = (jt < 32) ? 31 : 32;  // jt<32: d=32 pair arrived via rowscratch side
    const int si0 = 11 * (wave - 1);
    const int si1 = (wave == 3) ? ns : (si0 + 11);
    for (int si = si0; si < si1; ++si)
      s += colscratch[(jt * 32 + si) * 128 + rb + lane];
  }
  float* sp = (float*)colred;
  sp[wave * 64 + lane] = s;
  __syncthreads();
  float v = 0.0f;
  if (wave == 0) {
    const float tot = sp[lane] + sp[64 + lane] + sp[128 + lane] + sp[192 + lane];
    v = logf(tot) * (1.0f / (float)TWO_N);
  } else if (wave == 1 && lane < 32) {
    v = -pos[bid * 32 + lane] * (INV_T / (float)N_ROWS);
  }
  #pragma unroll
  for (int m = 1; m < 64; m <<= 1) v += __shfl_xor(v, m, 64);
  __syncthreads();
  if (lane == 0) sp[wave] = v;
  __syncthreads();
  if (tid == 0) atomicAdd(out, sp[0] + sp[1] + sp[2] + sp[3]);
}

extern "C" void kernel_launch(void* const* d_in, const int* in_sizes, int n_in,
                              void* d_out, int out_size, void* d_ws, size_t ws_size,
                              hipStream_t stream) {
  const float* z1 = (const float*)d_in[0];
  const float* z2 = (const float*)d_in[1];
  char* ws = (char*)d_ws;
  unsigned char* reps = (unsigned char*)ws;                // 8192*256 = 2 MB fp8
  size_t off = (size_t)TWO_N * ZDIM;
  float* pos = (float*)(ws + off);        off += N_ROWS * 4;        // 16 KB
  float* rowscratch = (float*)(ws + off); off += 64 * 8 * 128 * 4;  // 256 KB
  float* colscratch = (float*)(ws + off); off += 64 * 32 * 128 * 4; // 1 MB
  unsigned long long* flags1 = (unsigned long long*)(ws + off); off += 512 * 8;
  unsigned long long* flags2 = (unsigned long long*)(ws + off); off += 512 * 8;

  fused_kernel<<<dim3(64, 8), 256, 0, stream>>>(z1, z2, reps, pos, rowscratch,
                                                colscratch, flags1, flags2,
                                                (float*)d_out);
}

// Round 10
// 110.536 us; speedup vs baseline: 2.2303x; 2.2303x over previous
//
#include <hip/hip_runtime.h>
#include <hip/hip_bf16.h>

#define N_ROWS 4096
#define TWO_N  8192
#define ZDIM   256
#define INV_T  (1.0f/0.07f)
// exp((s-1)/T) = exp2((s-1) * INV_T * log2(e))
#define EXP_SCALE (INV_T * 1.44269504088896340736f)

typedef __attribute__((ext_vector_type(4))) float f32x4;

__device__ __forceinline__ void async_load16(const void* g, void* lds_uniform_base) {
  // HW computes LDS dest = (wave-uniform base) + lane*16; pass base WITHOUT lane term.
  __builtin_amdgcn_global_load_lds(
      (const __attribute__((address_space(1))) void*)g,
      (__attribute__((address_space(3))) void*)lds_uniform_base, 16, 0, 0);
}

// float -> OCP e4m3fn, round-to-nearest-even. Inputs here are |x| <= 1.
__device__ __forceinline__ unsigned char f32_to_e4m3(float x) {
  unsigned int u = __float_as_uint(x);
  const unsigned int s = u >> 31;
  unsigned int a = u & 0x7FFFFFFFu;
  if (a > 0x43E00000u) a = 0x43E00000u;
  const float f = __uint_as_float(a);
  unsigned int out;
  if (a < (121u << 23)) {                        // |x| < 2^-6: subnormal, step 2^-9
    const int m = (int)rintf(f * 512.0f);
    out = (unsigned int)m;
  } else {
    const unsigned int r = a + 0x7FFFFu + ((a >> 20) & 1u);  // RNE to 3 mantissa bits
    const unsigned int e8 = (r >> 23) - 120u;
    out = (e8 << 3) | ((r >> 20) & 7u);
  }
  return (unsigned char)(out | (s << 7));
}

// ---------------- Kernel A: wave-per-row normalize -> fp8 reps, fp32 pos ---------------
__global__ __launch_bounds__(256) void normalize_kernel(
    const float* __restrict__ z1, const float* __restrict__ z2,
    unsigned char* __restrict__ reps, float* __restrict__ pos,
    float* __restrict__ out) {
  const int lane = threadIdx.x & 63;
  const int wave = threadIdx.x >> 6;
  const int r = blockIdx.x * 4 + wave;
  const float4 a = ((const float4*)(z1 + (size_t)r * ZDIM))[lane];
  const float4 b = ((const float4*)(z2 + (size_t)r * ZDIM))[lane];
  float s1 = a.x*a.x + a.y*a.y + a.z*a.z + a.w*a.w;
  float s2 = b.x*b.x + b.y*b.y + b.z*b.z + b.w*b.w;
  float s3 = a.x*b.x + a.y*b.y + a.z*b.z + a.w*b.w;
  #pragma unroll
  for (int m = 1; m < 64; m <<= 1) {
    s1 += __shfl_xor(s1, m, 64);
    s2 += __shfl_xor(s2, m, 64);
    s3 += __shfl_xor(s3, m, 64);
  }
  const float inv1 = 1.0f / fmaxf(sqrtf(s1), 1e-12f);
  const float inv2 = 1.0f / fmaxf(sqrtf(s2), 1e-12f);
  uchar4 pa, pb;
  pa.x = f32_to_e4m3(a.x * inv1); pa.y = f32_to_e4m3(a.y * inv1);
  pa.z = f32_to_e4m3(a.z * inv1); pa.w = f32_to_e4m3(a.w * inv1);
  pb.x = f32_to_e4m3(b.x * inv2); pb.y = f32_to_e4m3(b.y * inv2);
  pb.z = f32_to_e4m3(b.z * inv2); pb.w = f32_to_e4m3(b.w * inv2);
  ((uchar4*)(reps + (size_t)r * ZDIM))[lane] = pa;
  ((uchar4*)(reps + (size_t)(r + N_ROWS) * ZDIM))[lane] = pb;
  if (lane == 0) {
    pos[r] = s3 * inv1 * inv2;
    if (r == 0) out[0] = INV_T;   // reduce_kernel atomically adds partials onto this
  }
}

// ---------------- Kernel B: triangular fp8 simsum, B direct L2->VGPR, 1 barrier ---------
// sim symmetric: each unordered 128x128 tile-pair once. Row-tile i, chunk c in 0..7:
//   c==0: d={0(diag),1,2,3} (+32 if i<32); c>0: d={4c..4c+3}; j=(i+d)&63.
// A tile (128x256 fp8, 32 KB) staged once to LDS (ONE barrier total). B fragments are
// loaded STRAIGHT from global (L2-resident, 2 MB) into VGPRs, ping-pong prefetched one
// K=128 half ahead (~64 MFMA in flight over each load batch > L2 latency). No B staging,
// no per-tile barriers, no vmcnt(0) drains in the loop (R9 lesson: device-scope fences /
// barrier drains are what this chip punishes). Row sums -> rowscratch[i][chunk][wn][128],
// col sums -> colscratch[j][d-1][wm][128] — every slot written by exactly one wave-pair
// with disjoint lanes: plain stores, zero atomics, zero end barriers.
__global__ __launch_bounds__(256, 2) void simsum_kernel(
    const unsigned char* __restrict__ reps,
    float* __restrict__ rowscratch,   // [64][8][2][128]
    float* __restrict__ colscratch) { // [64][32][2][128]
  __shared__ __align__(16) unsigned char Alds[128 * 256];  // 32 KB (total LDS)

  const int tid  = threadIdx.x;
  const int lane = tid & 63;
  const int wave = tid >> 6;
  const int wm = wave >> 1, wn = wave & 1;   // 2x2 wave grid
  const int quad = lane >> 4;                // 0..3
  const int l16  = lane & 15;
  const int itile = blockIdx.x;              // row tile 0..63
  const int chunk = blockIdx.y;              // distance chunk 0..7
  const int rowBase = itile * 128;
  const char* gbase = (const char*)reps;

  // ---- stage A tile (once): rows [rowBase,+128), 256B/row = 16 16B-chunks.
  // LDS 16B-slot (row,k16) holds global k16' = (k16&8)|((k16^row)&7) [XOR-low3 swizzle]
  {
    const int r0 = tid >> 4;
    const int src = (tid & 8) | ((tid ^ (tid >> 4)) & 7);
    const char* g0 = gbase + (rowBase + r0) * ZDIM + src * 16;
    char* l0 = (char*)Alds + (wave << 10);
    #pragma unroll
    for (int p = 0; p < 8; ++p)
      async_load16(g0 + p * 16 * ZDIM, l0 + p * 4096);
  }

  int doff[5];
  int nd;
  if (chunk == 0) {
    doff[0] = 0; doff[1] = 1; doff[2] = 2; doff[3] = 3; doff[4] = 32;
    nd = (itile < 32) ? 5 : 4;
  } else {
    doff[0] = chunk * 4; doff[1] = chunk * 4 + 1;
    doff[2] = chunk * 4 + 2; doff[3] = chunk * 4 + 3;
    doff[4] = 0;
    nd = 4;
  }
  const int Q = nd * 2;   // halves: tile t = q>>1, k-half c = q&1 (Q always even)

  // Prefetch B fragments for half q into a 16-long register buffer.
  // B octet for (ni, kstep s): row n = jt*128 + wn*64 + ni*16 + l16,
  // byte = n*256 + (c*16 + s*4 + quad)*8 = n*256 + c*128 + s*32 + quad*8.
#define PREF(q_, buf_) do {                                                     \
    const int t_ = (q_) >> 1, c_ = (q_) & 1;                                    \
    const int jt_ = (itile + doff[t_]) & 63;                                    \
    const char* bp_ = gbase + (size_t)(jt_ * 128 + wn * 64 + l16) * ZDIM        \
                      + c_ * 128 + quad * 8;                                    \
    _Pragma("unroll")                                                           \
    for (int ni_ = 0; ni_ < 4; ++ni_)                                           \
      _Pragma("unroll")                                                         \
      for (int s_ = 0; s_ < 4; ++s_)                                            \
        buf_[ni_ * 4 + s_] = *(const long*)(bp_ + ni_ * 16 * ZDIM + s_ * 32);   \
  } while (0)

  // 4 k-steps (K=32 each) of half c of tile q>>1; A from LDS, B from buf_.
#define KSTEPS(c_, buf_) do {                                                   \
    _Pragma("unroll")                                                           \
    for (int ws_ = 0; ws_ < 4; ++ws_) {                                         \
      const int o_ = (c_) * 16 + ws_ * 4 + quad;                                \
      const int k16_ = o_ >> 1, h_ = (o_ & 1) * 8;                              \
      long afrag_[4];                                                           \
      _Pragma("unroll")                                                         \
      for (int mi_ = 0; mi_ < 4; ++mi_) {                                       \
        const int m_ = wm * 64 + mi_ * 16 + l16;                                \
        const int sw_ = (k16_ & 8) | ((k16_ ^ m_) & 7);                         \
        afrag_[mi_] = *(const long*)((const char*)Alds + m_ * 256 + sw_ * 16 + h_); \
      }                                                                         \
      _Pragma("unroll")                                                         \
      for (int mi_ = 0; mi_ < 4; ++mi_)                                         \
        _Pragma("unroll")                                                       \
        for (int ni_ = 0; ni_ < 4; ++ni_)                                       \
          acc[mi_][ni_] = __builtin_amdgcn_mfma_f32_16x16x32_fp8_fp8(           \
              afrag_[mi_], buf_[ni_ * 4 + ws_], acc[mi_][ni_], 0, 0, 0);        \
    }                                                                           \
  } while (0)

  float rowpart[16];
  #pragma unroll
  for (int i = 0; i < 16; ++i) rowpart[i] = 0.0f;
  const f32x4 zero4 = {0.0f, 0.0f, 0.0f, 0.0f};

  long b0[16], b1[16];
  f32x4 acc[4][4];

  PREF(0, b0);
  __syncthreads();          // the ONE barrier: A staged (drains A + prefetch(0), fine)

  for (int q = 0; q < Q; q += 2) {
    if (q + 1 < Q) PREF(q + 1, b1);      // in flight across KSTEPS(0)
    #pragma unroll
    for (int mi = 0; mi < 4; ++mi)
      #pragma unroll
      for (int ni = 0; ni < 4; ++ni) acc[mi][ni] = zero4;
    KSTEPS(0, b0);

    if (q + 2 < Q) PREF(q + 2, b0);      // in flight across KSTEPS(1) + epilogue
    KSTEPS(1, b1);

    // ---- tile complete: exp epilogue, all-register/shfl, no LDS, no barrier ----
    const int t = q >> 1;
    const int d = doff[t];
    const int jtile = (itile + d) & 63;
    const bool diag = (d == 0);
    float colpart[4] = {0.0f, 0.0f, 0.0f, 0.0f};
    #pragma unroll
    for (int mi = 0; mi < 4; ++mi)
      #pragma unroll
      for (int r = 0; r < 4; ++r) {
        const int grow = rowBase + wm * 64 + mi * 16 + quad * 4 + r;
        float s = 0.0f;
        #pragma unroll
        for (int ni = 0; ni < 4; ++ni) {
          const int gcol = jtile * 128 + wn * 64 + ni * 16 + l16;
          const float e = exp2f((acc[mi][ni][r] - 1.0f) * EXP_SCALE);
          if (!diag || grow != gcol) s += e;
          colpart[ni] += e;
        }
        rowpart[mi * 4 + r] += s;
      }
    if (!diag) {
      #pragma unroll
      for (int ni = 0; ni < 4; ++ni) {
        float v = colpart[ni];
        v += __shfl_xor(v, 16, 64);   // reduce across the 4 quads (frag rows)
        v += __shfl_xor(v, 32, 64);
        if (quad == 0)
          colscratch[(((jtile * 32) + (d - 1)) * 2 + wm) * 128 + wn * 64 + ni * 16 + l16] = v;
      }
    }
  }
#undef PREF
#undef KSTEPS

  // ---- row partials: shfl over the 16 col-lanes; wn-halves go to SEPARATE slots
  // (both wn waves cover the same rows — separate slots instead of a racy merge) ----
  #pragma unroll
  for (int i = 0; i < 16; ++i) {
    float v = rowpart[i];
    v += __shfl_xor(v, 1, 64);
    v += __shfl_xor(v, 2, 64);
    v += __shfl_xor(v, 4, 64);
    v += __shfl_xor(v, 8, 64);
    rowpart[i] = v;
  }
  if (l16 == 0) {
    #pragma unroll
    for (int mi = 0; mi < 4; ++mi)
      #pragma unroll
      for (int r = 0; r < 4; ++r)
        rowscratch[((itile * 8 + chunk) * 2 + wn) * 128 + wm * 64 + mi * 16 + quad * 4 + r]
            = rowpart[mi * 4 + r];
  }
}

// ---------------- Kernel C: gather partials per row, logf, add partial loss -------------
// Grid 64 blocks: block j handles rows [j*128,+128) and pos[j*64,+64).
// out pre-set to 1/T by normalize; each block atomicAdds its partial (64 atomics).
__global__ __launch_bounds__(256) void reduce_kernel(
    const float* __restrict__ rowscratch, const float* __restrict__ colscratch,
    const float* __restrict__ pos, float* __restrict__ out) {
  const int j = blockIdx.x;
  const int tid = threadIdx.x;
  float v = 0.0f;
  if (tid < 128) {
    float s = 0.0f;
    #pragma unroll
    for (int c = 0; c < 8; ++c)
      #pragma unroll
      for (int w = 0; w < 2; ++w)
        s += rowscratch[((j * 8 + c) * 2 + w) * 128 + tid];
    const int ns = (j < 32) ? 31 : 32;   // j<32: the d=32 pair arrived via rowscratch side
    for (int si = 0; si < ns; ++si)
      #pragma unroll
      for (int w = 0; w < 2; ++w)
        s += colscratch[((j * 32 + si) * 2 + w) * 128 + tid];
    v = logf(s) * (1.0f / (float)TWO_N);
  } else if (tid < 192) {
    v = -pos[j * 64 + (tid - 128)] * (INV_T / (float)N_ROWS);
  }
  #pragma unroll
  for (int m = 1; m < 64; m <<= 1) v += __shfl_xor(v, m, 64);
  __shared__ float red[4];
  if ((tid & 63) == 0) red[tid >> 6] = v;
  __syncthreads();
  if (tid == 0) atomicAdd(out, red[0] + red[1] + red[2] + red[3]);
}

extern "C" void kernel_launch(void* const* d_in, const int* in_sizes, int n_in,
                              void* d_out, int out_size, void* d_ws, size_t ws_size,
                              hipStream_t stream) {
  const float* z1 = (const float*)d_in[0];
  const float* z2 = (const float*)d_in[1];
  char* ws = (char*)d_ws;
  unsigned char* reps = (unsigned char*)ws;                // 8192*256 = 2 MB fp8
  size_t off = (size_t)TWO_N * ZDIM;
  float* pos = (float*)(ws + off);        off += N_ROWS * 4;            // 16 KB
  float* rowscratch = (float*)(ws + off); off += 64 * 8 * 2 * 128 * 4;  // 512 KB
  float* colscratch = (float*)(ws + off); off += 64 * 32 * 2 * 128 * 4; // 2 MB

  normalize_kernel<<<1024, 256, 0, stream>>>(z1, z2, reps, pos, (float*)d_out);
  simsum_kernel<<<dim3(64, 8), 256, 0, stream>>>(reps, rowscratch, colscratch);
  reduce_kernel<<<64, 256, 0, stream>>>(rowscratch, colscratch, pos, (float*)d_out);
}

// Round 11
// 104.101 us; speedup vs baseline: 2.3682x; 1.0618x over previous
//
#include <hip/hip_runtime.h>
#include <hip/hip_bf16.h>

#define N_ROWS 4096
#define TWO_N  8192
#define ZDIM   256
#define INV_T  (1.0f/0.07f)
// exp((s-1)/T) = exp2((s-1) * INV_T * log2(e))
#define EXP_SCALE (INV_T * 1.44269504088896340736f)

typedef __attribute__((ext_vector_type(4))) float f32x4;

__device__ __forceinline__ void async_load16(const void* g, void* lds_uniform_base) {
  // HW computes LDS dest = (wave-uniform base) + lane*16; pass base WITHOUT lane term.
  __builtin_amdgcn_global_load_lds(
      (const __attribute__((address_space(1))) void*)g,
      (__attribute__((address_space(3))) void*)lds_uniform_base, 16, 0, 0);
}

// float -> OCP e4m3fn, round-to-nearest-even. Inputs here are |x| <= 1.
__device__ __forceinline__ unsigned char f32_to_e4m3(float x) {
  unsigned int u = __float_as_uint(x);
  const unsigned int s = u >> 31;
  unsigned int a = u & 0x7FFFFFFFu;
  if (a > 0x43E00000u) a = 0x43E00000u;
  const float f = __uint_as_float(a);
  unsigned int out;
  if (a < (121u << 23)) {                        // |x| < 2^-6: subnormal, step 2^-9
    const int m = (int)rintf(f * 512.0f);
    out = (unsigned int)m;
  } else {
    const unsigned int r = a + 0x7FFFFu + ((a >> 20) & 1u);  // RNE to 3 mantissa bits
    const unsigned int e8 = (r >> 23) - 120u;
    out = (e8 << 3) | ((r >> 20) & 7u);
  }
  return (unsigned char)(out | (s << 7));
}

// ---------------- Kernel A: wave-per-row normalize -> fp8 reps, fp32 pos ---------------
__global__ __launch_bounds__(256) void normalize_kernel(
    const float* __restrict__ z1, const float* __restrict__ z2,
    unsigned char* __restrict__ reps, float* __restrict__ pos,
    float* __restrict__ out) {
  const int lane = threadIdx.x & 63;
  const int wave = threadIdx.x >> 6;
  const int r = blockIdx.x * 4 + wave;
  const float4 a = ((const float4*)(z1 + (size_t)r * ZDIM))[lane];
  const float4 b = ((const float4*)(z2 + (size_t)r * ZDIM))[lane];
  float s1 = a.x*a.x + a.y*a.y + a.z*a.z + a.w*a.w;
  float s2 = b.x*b.x + b.y*b.y + b.z*b.z + b.w*b.w;
  float s3 = a.x*b.x + a.y*b.y + a.z*b.z + a.w*b.w;
  #pragma unroll
  for (int m = 1; m < 64; m <<= 1) {
    s1 += __shfl_xor(s1, m, 64);
    s2 += __shfl_xor(s2, m, 64);
    s3 += __shfl_xor(s3, m, 64);
  }
  const float inv1 = 1.0f / fmaxf(sqrtf(s1), 1e-12f);
  const float inv2 = 1.0f / fmaxf(sqrtf(s2), 1e-12f);
  uchar4 pa, pb;
  pa.x = f32_to_e4m3(a.x * inv1); pa.y = f32_to_e4m3(a.y * inv1);
  pa.z = f32_to_e4m3(a.z * inv1); pa.w = f32_to_e4m3(a.w * inv1);
  pb.x = f32_to_e4m3(b.x * inv2); pb.y = f32_to_e4m3(b.y * inv2);
  pb.z = f32_to_e4m3(b.z * inv2); pb.w = f32_to_e4m3(b.w * inv2);
  ((uchar4*)(reps + (size_t)r * ZDIM))[lane] = pa;
  ((uchar4*)(reps + (size_t)(r + N_ROWS) * ZDIM))[lane] = pb;
  if (lane == 0) {
    pos[r] = s3 * inv1 * inv2;
    if (r == 0) out[0] = INV_T;   // reduce_kernel atomically adds partials onto this
  }
}

// ---------------- Kernel B: triangular fp8 simsum, K=64 quarters, 3 blocks/CU -----------
// sim symmetric: each unordered 128x128 tile-pair once. Row-tile i, chunk c in 0..15:
//   c==0: d={0(diag),1} (+32 if i<32); c>0: d={2c,2c+1}; j=(i+d)&63.
// A tile (128x256 fp8, 32 KB) staged once. B staged in K=64 QUARTERS into 2x8 KB
// ping-pong buffers, stage(q+1) issued before compute(q) (drain always covered).
// LDS = 48 KB -> 3 blocks/CU (12 waves/CU, 3 waves/SIMD): one more sibling block to
// cover every barrier/drain stall than the 2-blk/CU plateau of R4/R6/R7. Grid (64,16)
// = 1024 blocks (~2 tiles each) so the extra residency is used.
// Row sums -> rowscratch[i][chunk][wn][128], col sums -> colscratch[j][d-1][wm][128]:
// each slot written by one wave with disjoint lanes — plain stores, zero atomics.
__global__ __launch_bounds__(256, 3) void simsum_kernel(
    const unsigned char* __restrict__ reps,
    float* __restrict__ rowscratch,   // [64][16][2][128]
    float* __restrict__ colscratch) { // [64][32][2][128]
  __shared__ __align__(16) unsigned char Alds[128 * 256];    // 32 KB
  __shared__ __align__(16) unsigned char Blds[2][128 * 64];  // 2 x 8 KB (total 48 KB)

  const int tid  = threadIdx.x;
  const int lane = tid & 63;
  const int wave = tid >> 6;
  const int wm = wave >> 1, wn = wave & 1;   // 2x2 wave grid
  const int quad = lane >> 4;                // 0..3
  const int l16  = lane & 15;
  const int itile = blockIdx.x;              // row tile 0..63
  const int chunk = blockIdx.y;              // distance chunk 0..15
  const int rowBase = itile * 128;
  const char* gbase = (const char*)reps;

  // ---- stage A tile (once): rows [rowBase,+128), 256B/row = 16 16B-chunks.
  // LDS 16B-slot (row,k16) holds global k16' = (k16&8)|((k16^row)&7) [XOR-low3 swizzle]
  {
    const int r0 = tid >> 4;
    const int src = (tid & 8) | ((tid ^ (tid >> 4)) & 7);
    const char* g0 = gbase + (rowBase + r0) * ZDIM + src * 16;
    char* l0 = (char*)Alds + (wave << 10);
    #pragma unroll
    for (int p = 0; p < 8; ++p)
      async_load16(g0 + p * 16 * ZDIM, l0 + p * 4096);
  }

  int doff[3];
  int nd;
  if (chunk == 0) {
    doff[0] = 0; doff[1] = 1; doff[2] = 32;
    nd = (itile < 32) ? 3 : 2;
  } else {
    doff[0] = 2 * chunk; doff[1] = 2 * chunk + 1; doff[2] = 0;
    nd = 2;
  }
  const int Q = nd * 4;   // quarter-steps: tile t = q>>2, quarter c4 = q&3

  // Stage B quarter q: rows [jt*128,+128), k-bytes [c4*64,+64). 8 KB = 512 16B-chunks;
  // LDS slot (row, sl in 0..3) holds global 16B-chunk sl^(row&3) of the quarter.
#define STAGE_B(q_) do {                                                        \
    const int t_ = (q_) >> 2, c4_ = (q_) & 3;                                   \
    const int jt_ = (itile + doff[t_]) & 63;                                    \
    _Pragma("unroll")                                                           \
    for (int p_ = 0; p_ < 2; ++p_) {                                            \
      const int c_ = p_ * 256 + (wave << 6) + lane;                             \
      const int row_ = c_ >> 2, sl_ = c_ & 3;                                   \
      const int g_ = sl_ ^ (row_ & 3);                                          \
      async_load16(gbase + (size_t)(jt_ * 128 + row_) * ZDIM + c4_ * 64 + g_ * 16, \
                   (char*)Blds[(q_) & 1] + p_ * 4096 + (wave << 10));           \
    }                                                                           \
  } while (0)

  float rowpart[16];
  #pragma unroll
  for (int i = 0; i < 16; ++i) rowpart[i] = 0.0f;
  const f32x4 zero4 = {0.0f, 0.0f, 0.0f, 0.0f};

  STAGE_B(0);
  __syncthreads();          // drains A + stage(0)

  f32x4 acc[4][4];
  for (int q = 0; q < Q; ++q) {
    if (q + 1 < Q) STAGE_B(q + 1);    // in flight across compute(q)
    const int t = q >> 2, c4 = q & 3;
    const int d = doff[t];
    const int jtile = (itile + d) & 63;
    const bool diag = (d == 0);

    if (c4 == 0) {
      #pragma unroll
      for (int mi = 0; mi < 4; ++mi)
        #pragma unroll
        for (int ni = 0; ni < 4; ++ni) acc[mi][ni] = zero4;
    }

    // 2 K=32 k-steps of this K=64 quarter; A from Alds, B from Blds[q&1].
    #pragma unroll
    for (int kk = 0; kk < 2; ++kk) {
      const int ol = kk * 4 + quad;            // quarter-local octet 0..7
      const int o  = c4 * 8 + ol;              // global octet 0..31
      const int k16 = o >> 1, half = (o & 1) * 8;
      const int sl = ol >> 1, halfl = (ol & 1) * 8;
      long afrag[4], bfrag[4];
      #pragma unroll
      for (int mi = 0; mi < 4; ++mi) {
        const int m = wm * 64 + mi * 16 + l16;
        const int sw = (k16 & 8) | ((k16 ^ m) & 7);
        afrag[mi] = *(const long*)((const char*)Alds + m * 256 + sw * 16 + half);
      }
      #pragma unroll
      for (int ni = 0; ni < 4; ++ni) {
        const int n = wn * 64 + ni * 16 + l16;
        const int sw = sl ^ (n & 3);
        bfrag[ni] = *(const long*)((const char*)Blds[q & 1] + n * 64 + sw * 16 + halfl);
      }
      #pragma unroll
      for (int mi = 0; mi < 4; ++mi)
        #pragma unroll
        for (int ni = 0; ni < 4; ++ni)
          acc[mi][ni] = __builtin_amdgcn_mfma_f32_16x16x32_fp8_fp8(
              afrag[mi], bfrag[ni], acc[mi][ni], 0, 0, 0);
    }

    if (c4 == 3) {
      // ---- tile complete: exp epilogue, registers/shfl only, no LDS ----
      float colpart[4] = {0.0f, 0.0f, 0.0f, 0.0f};
      #pragma unroll
      for (int mi = 0; mi < 4; ++mi)
        #pragma unroll
        for (int r = 0; r < 4; ++r) {
          const int grow = rowBase + wm * 64 + mi * 16 + quad * 4 + r;
          float s = 0.0f;
          #pragma unroll
          for (int ni = 0; ni < 4; ++ni) {
            const int gcol = jtile * 128 + wn * 64 + ni * 16 + l16;
            const float e = exp2f((acc[mi][ni][r] - 1.0f) * EXP_SCALE);
            if (!diag || grow != gcol) s += e;
            colpart[ni] += e;
          }
          rowpart[mi * 4 + r] += s;
        }
      if (!diag) {
        #pragma unroll
        for (int ni = 0; ni < 4; ++ni) {
          float v = colpart[ni];
          v += __shfl_xor(v, 16, 64);   // reduce across the 4 quads (frag rows)
          v += __shfl_xor(v, 32, 64);
          if (quad == 0)
            colscratch[(((jtile * 32) + (d - 1)) * 2 + wm) * 128 + wn * 64 + ni * 16 + l16] = v;
        }
      }
    }
    __syncthreads();   // drains stage(q+1); frees Blds[q&1] for stage(q+2)
  }
#undef STAGE_B

  // ---- row partials: shfl over the 16 col-lanes; wn-halves to SEPARATE slots
  // (both wn waves cover the same rows — separate slots, no merge, no race) ----
  #pragma unroll
  for (int i = 0; i < 16; ++i) {
    float v = rowpart[i];
    v += __shfl_xor(v, 1, 64);
    v += __shfl_xor(v, 2, 64);
    v += __shfl_xor(v, 4, 64);
    v += __shfl_xor(v, 8, 64);
    rowpart[i] = v;
  }
  if (l16 == 0) {
    #pragma unroll
    for (int mi = 0; mi < 4; ++mi)
      #pragma unroll
      for (int r = 0; r < 4; ++r)
        rowscratch[((itile * 16 + chunk) * 2 + wn) * 128 + wm * 64 + mi * 16 + quad * 4 + r]
            = rowpart[mi * 4 + r];
  }
}

// ---------------- Kernel C: gather partials per row, logf, add partial loss -------------
// Grid 64 blocks: block j handles rows [j*128,+128) and pos[j*64,+64).
// out pre-set to 1/T by normalize; each block atomicAdds its partial (64 atomics).
__global__ __launch_bounds__(256) void reduce_kernel(
    const float* __restrict__ rowscratch, const float* __restrict__ colscratch,
    const float* __restrict__ pos, float* __restrict__ out) {
  const int j = blockIdx.x;
  const int tid = threadIdx.x;
  float v = 0.0f;
  if (tid < 128) {
    float s = 0.0f;
    #pragma unroll
    for (int c = 0; c < 16; ++c)
      #pragma unroll
      for (int w = 0; w < 2; ++w)
        s += rowscratch[((j * 16 + c) * 2 + w) * 128 + tid];
    const int ns = (j < 32) ? 31 : 32;   // j<32: the d=32 pair arrived via rowscratch side
    for (int si = 0; si < ns; ++si)
      #pragma unroll
      for (int w = 0; w < 2; ++w)
        s += colscratch[((j * 32 + si) * 2 + w) * 128 + tid];
    v = logf(s) * (1.0f / (float)TWO_N);
  } else if (tid < 192) {
    v = -pos[j * 64 + (tid - 128)] * (INV_T / (float)N_ROWS);
  }
  #pragma unroll
  for (int m = 1; m < 64; m <<= 1) v += __shfl_xor(v, m, 64);
  __shared__ float red[4];
  if ((tid & 63) == 0) red[tid >> 6] = v;
  __syncthreads();
  if (tid == 0) atomicAdd(out, red[0] + red[1] + red[2] + red[3]);
}

extern "C" void kernel_launch(void* const* d_in, const int* in_sizes, int n_in,
                              void* d_out, int out_size, void* d_ws, size_t ws_size,
                              hipStream_t stream) {
  const float* z1 = (const float*)d_in[0];
  const float* z2 = (const float*)d_in[1];
  char* ws = (char*)d_ws;
  unsigned char* reps = (unsigned char*)ws;                // 8192*256 = 2 MB fp8
  size_t off = (size_t)TWO_N * ZDIM;
  float* pos = (float*)(ws + off);        off += N_ROWS * 4;             // 16 KB
  float* rowscratch = (float*)(ws + off); off += 64 * 16 * 2 * 128 * 4;  // 1 MB
  float* colscratch = (float*)(ws + off); off += 64 * 32 * 2 * 128 * 4;  // 2 MB

  normalize_kernel<<<1024, 256, 0, stream>>>(z1, z2, reps, pos, (float*)d_out);
  simsum_kernel<<<dim3(64, 16), 256, 0, stream>>>(reps, rowscratch, colscratch);
  reduce_kernel<<<64, 256, 0, stream>>>(rowscratch, colscratch, pos, (float*)d_out);
}

// Round 12
// 96.636 us; speedup vs baseline: 2.5511x; 1.0772x over previous
//
#include <hip/hip_runtime.h>
#include <hip/hip_bf16.h>

#define N_ROWS 4096
#define TWO_N  8192
#define ZDIM   256
#define INV_T  (1.0f/0.07f)
// exp(s/T) = exp2(s * INV_T * log2(e)); the -1/T is folded into the final loss constant
#define EXP_SCALE (INV_T * 1.44269504088896340736f)

typedef __attribute__((ext_vector_type(4))) float f32x4;

__device__ __forceinline__ void async_load16(const void* g, void* lds_uniform_base) {
  // HW computes LDS dest = (wave-uniform base) + lane*16; pass base WITHOUT lane term.
  __builtin_amdgcn_global_load_lds(
      (const __attribute__((address_space(1))) void*)g,
      (__attribute__((address_space(3))) void*)lds_uniform_base, 16, 0, 0);
}

// float -> OCP e4m3fn, round-to-nearest-even. Inputs here are |x| <= 1.
__device__ __forceinline__ unsigned char f32_to_e4m3(float x) {
  unsigned int u = __float_as_uint(x);
  const unsigned int s = u >> 31;
  unsigned int a = u & 0x7FFFFFFFu;
  if (a > 0x43E00000u) a = 0x43E00000u;
  const float f = __uint_as_float(a);
  unsigned int out;
  if (a < (121u << 23)) {                        // |x| < 2^-6: subnormal, step 2^-9
    const int m = (int)rintf(f * 512.0f);
    out = (unsigned int)m;
  } else {
    const unsigned int r = a + 0x7FFFFu + ((a >> 20) & 1u);  // RNE to 3 mantissa bits
    const unsigned int e8 = (r >> 23) - 120u;
    out = (e8 << 3) | ((r >> 20) & 7u);
  }
  return (unsigned char)(out | (s << 7));
}

// ---------------- Kernel A: wave-per-row normalize -> fp8 reps, fp32 pos ---------------
__global__ __launch_bounds__(256) void normalize_kernel(
    const float* __restrict__ z1, const float* __restrict__ z2,
    unsigned char* __restrict__ reps, float* __restrict__ pos,
    float* __restrict__ out) {
  const int lane = threadIdx.x & 63;
  const int wave = threadIdx.x >> 6;
  const int r = blockIdx.x * 4 + wave;
  const float4 a = ((const float4*)(z1 + (size_t)r * ZDIM))[lane];
  const float4 b = ((const float4*)(z2 + (size_t)r * ZDIM))[lane];
  float s1 = a.x*a.x + a.y*a.y + a.z*a.z + a.w*a.w;
  float s2 = b.x*b.x + b.y*b.y + b.z*b.z + b.w*b.w;
  float s3 = a.x*b.x + a.y*b.y + a.z*b.z + a.w*b.w;
  #pragma unroll
  for (int m = 1; m < 64; m <<= 1) {
    s1 += __shfl_xor(s1, m, 64);
    s2 += __shfl_xor(s2, m, 64);
    s3 += __shfl_xor(s3, m, 64);
  }
  const float inv1 = 1.0f / fmaxf(sqrtf(s1), 1e-12f);
  const float inv2 = 1.0f / fmaxf(sqrtf(s2), 1e-12f);
  uchar4 pa, pb;
  pa.x = f32_to_e4m3(a.x * inv1); pa.y = f32_to_e4m3(a.y * inv1);
  pa.z = f32_to_e4m3(a.z * inv1); pa.w = f32_to_e4m3(a.w * inv1);
  pb.x = f32_to_e4m3(b.x * inv2); pb.y = f32_to_e4m3(b.y * inv2);
  pb.z = f32_to_e4m3(b.z * inv2); pb.w = f32_to_e4m3(b.w * inv2);
  ((uchar4*)(reps + (size_t)r * ZDIM))[lane] = pa;
  ((uchar4*)(reps + (size_t)(r + N_ROWS) * ZDIM))[lane] = pb;
  if (lane == 0) {
    pos[r] = s3 * inv1 * inv2;
    if (r == 0) out[0] = 0.0f;  // -1/T folded: loss = mean(log rs) - mean(pos)/T
  }
}

// ---------------- Kernel B: triangular fp8 simsum, (64,16) grid, K=128 ping-pong --------
// sim symmetric: each unordered 128x128 tile-pair once. Row-tile i, chunk c in 0..15:
//   c==0: diag (prologue) + d={1} (+32 if i<32); c>0: d={2c,2c+1}; j=(i+d)&63.
// 1024 blocks of ~2 tiles (vs R7's 512 of 4-5): the 2080-tile total packs dynamically
// onto 512 residency slots with a <=1-tile tail instead of R7's 25% straggler tail
// (32 five-tile blocks held the GPU ~5 us). Heavy 3-tile blocks are y=0 -> dispatched
// first and absorbed. A tile 32 KB staged once/block; B in K=128 halves, 2x16 KB
// ping-pong, stage(q+1) before compute(q) -> every drain covered; 2 barriers/tile.
// 64 KB LDS -> 2 blocks/CU. Row sums -> rowscratch[i][c][wn][128], col sums ->
// colscratch[j][d-1][wm][128]: every slot written by exactly one wave, disjoint lanes —
// plain stores, zero atomics, zero fences (kernel boundary publishes).
__global__ __launch_bounds__(256, 2) void simsum_kernel(
    const unsigned char* __restrict__ reps,
    float* __restrict__ rowscratch,   // [64][16][2][128]
    float* __restrict__ colscratch) { // [64][32][2][128]
  __shared__ __align__(16) unsigned char Alds[128 * 256];     // 32 KB
  __shared__ __align__(16) unsigned char Blds[2][128 * 128];  // 2 x 16 KB (total 64 KB)

  const int tid  = threadIdx.x;
  const int lane = tid & 63;
  const int wave = tid >> 6;
  const int wm = wave >> 1, wn = wave & 1;   // 2x2 wave grid
  const int quad = lane >> 4;                // 0..3
  const int l16  = lane & 15;
  const int itile = blockIdx.x;              // row tile 0..63
  const int chunk = blockIdx.y;              // distance chunk 0..15
  const int rowBase = itile * 128;
  const char* gbase = (const char*)reps;
  const bool diaghere = (chunk == 0);

  // ---- stage A tile (once): rows [rowBase,+128), 256B/row = 16 16B-chunks.
  // LDS 16B-slot (row,k16) holds global k16' = (k16&8)|((k16^row)&7) [XOR-low3 swizzle]
  {
    const int r0 = tid >> 4;
    const int src = (tid & 8) | ((tid ^ (tid >> 4)) & 7);
    const char* g0 = gbase + (rowBase + r0) * ZDIM + src * 16;
    char* l0 = (char*)Alds + (wave << 10);
    #pragma unroll
    for (int p = 0; p < 8; ++p)
      async_load16(g0 + p * 16 * ZDIM, l0 + p * 4096);
  }

  // off-diagonal d list for this block (diag handled in prologue for chunk 0)
  int doff[2];
  int noff;
  if (diaghere) {
    doff[0] = 1; doff[1] = 32;
    noff = (itile < 32) ? 2 : 1;
  } else {
    doff[0] = 2 * chunk; doff[1] = 2 * chunk + 1;
    noff = 2;
  }
  const int Q = noff * 2;   // K=128 half-steps: tile t = q>>1, half c = q&1

  // stage B half q: rows [jt*128,+128), k-bytes [c*128,+128). 128B/row = 8 16B-slots;
  // LDS slot (row, sl) holds global 16B-chunk (sl ^ (row&7)) of the half.
#define STAGE_B(q_) do {                                                        \
    const int t_ = (q_) >> 1, c_ = (q_) & 1;                                    \
    const int jt_ = (itile + doff[t_]) & 63;                                    \
    const int r0_ = tid >> 3;                                                   \
    const int src_ = (tid ^ (tid >> 3)) & 7;                                    \
    const char* g0_ = gbase + (jt_ * 128 + r0_) * ZDIM + c_ * 128 + src_ * 16;  \
    char* l0_ = (char*)Blds[(q_) & 1] + (wave << 10);                           \
    _Pragma("unroll")                                                           \
    for (int p_ = 0; p_ < 4; ++p_)                                              \
      async_load16(g0_ + p_ * 32 * ZDIM, l0_ + p_ * 4096);                      \
  } while (0)

  float rowpart[16];
  #pragma unroll
  for (int i = 0; i < 16; ++i) rowpart[i] = 0.0f;
  const f32x4 zero4 = {0.0f, 0.0f, 0.0f, 0.0f};

  // ---- prologue ----
  if (diaghere) {
    __syncthreads();                  // drain A
    if (Q > 0) STAGE_B(0);            // covered by the diag compute below
    f32x4 acc[4][4];
    #pragma unroll
    for (int mi = 0; mi < 4; ++mi)
      #pragma unroll
      for (int ni = 0; ni < 4; ++ni) acc[mi][ni] = zero4;
    #pragma unroll
    for (int w = 0; w < 8; ++w) {     // 8 K=32 windows, both operands from Alds
      const int o = w * 4 + quad;
      const int k16 = o >> 1, half = (o & 1) * 8;
      long afrag[4], bfrag[4];
      #pragma unroll
      for (int mi = 0; mi < 4; ++mi) {
        const int m = wm * 64 + mi * 16 + l16;
        const int sw = (k16 & 8) | ((k16 ^ m) & 7);
        afrag[mi] = *(const long*)((const char*)Alds + m * 256 + sw * 16 + half);
      }
      #pragma unroll
      for (int ni = 0; ni < 4; ++ni) {
        const int n = wn * 64 + ni * 16 + l16;
        const int sw = (k16 & 8) | ((k16 ^ n) & 7);
        bfrag[ni] = *(const long*)((const char*)Alds + n * 256 + sw * 16 + half);
      }
      #pragma unroll
      for (int mi = 0; mi < 4; ++mi)
        #pragma unroll
        for (int ni = 0; ni < 4; ++ni)
          acc[mi][ni] = __builtin_amdgcn_mfma_f32_16x16x32_fp8_fp8(
              afrag[mi], bfrag[ni], acc[mi][ni], 0, 0, 0);
    }
    // diag epilogue: rows only (tile is its own transpose), self term masked
    #pragma unroll
    for (int mi = 0; mi < 4; ++mi)
      #pragma unroll
      for (int r = 0; r < 4; ++r) {
        const int grow = rowBase + wm * 64 + mi * 16 + quad * 4 + r;
        float s = 0.0f;
        #pragma unroll
        for (int ni = 0; ni < 4; ++ni) {
          const int gcol = rowBase + wn * 64 + ni * 16 + l16;
          const float e = exp2f(acc[mi][ni][r] * EXP_SCALE);
          if (grow != gcol) s += e;
        }
        rowpart[mi * 4 + r] += s;
      }
    __syncthreads();                  // drain stage(0)
  } else {
    STAGE_B(0);
    __syncthreads();                  // drain A + stage(0)
  }

  // ---- pipelined main loop over K=128 halves ----
  f32x4 acc[4][4];
  for (int q = 0; q < Q; ++q) {
    if (q + 1 < Q) STAGE_B(q + 1);    // in flight during compute(q)
    const int t = q >> 1, c = q & 1;
    const int d = doff[t];
    const int jtile = (itile + d) & 63;

    if (c == 0) {
      #pragma unroll
      for (int mi = 0; mi < 4; ++mi)
        #pragma unroll
        for (int ni = 0; ni < 4; ++ni) acc[mi][ni] = zero4;
    }
    #pragma unroll
    for (int ws = 0; ws < 4; ++ws) {
      const int o  = c * 16 + ws * 4 + quad;   // global k-octet
      const int k16 = o >> 1, half = (o & 1) * 8;
      const int ol = ws * 4 + quad;            // half-local octet
      const int sl = ol >> 1, halfl = (ol & 1) * 8;
      long afrag[4], bfrag[4];
      #pragma unroll
      for (int mi = 0; mi < 4; ++mi) {
        const int m = wm * 64 + mi * 16 + l16;
        const int sw = (k16 & 8) | ((k16 ^ m) & 7);
        afrag[mi] = *(const long*)((const char*)Alds + m * 256 + sw * 16 + half);
      }
      #pragma unroll
      for (int ni = 0; ni < 4; ++ni) {
        const int n = wn * 64 + ni * 16 + l16;
        const int sw = sl ^ (n & 7);
        bfrag[ni] = *(const long*)((const char*)Blds[c] + n * 128 + sw * 16 + halfl);
      }
      #pragma unroll
      for (int mi = 0; mi < 4; ++mi)
        #pragma unroll
        for (int ni = 0; ni < 4; ++ni)
          acc[mi][ni] = __builtin_amdgcn_mfma_f32_16x16x32_fp8_fp8(
              afrag[mi], bfrag[ni], acc[mi][ni], 0, 0, 0);
    }

    if (c == 1) {
      // ---- tile complete: exp epilogue, registers/shfl only, no LDS ----
      const int dm1 = d - 1;
      float colpart[4] = {0.0f, 0.0f, 0.0f, 0.0f};
      #pragma unroll
      for (int mi = 0; mi < 4; ++mi)
        #pragma unroll
        for (int r = 0; r < 4; ++r) {
          float s = 0.0f;
          #pragma unroll
          for (int ni = 0; ni < 4; ++ni) {
            const float e = exp2f(acc[mi][ni][r] * EXP_SCALE);
            s += e;
            colpart[ni] += e;
          }
          rowpart[mi * 4 + r] += s;
        }
      #pragma unroll
      for (int ni = 0; ni < 4; ++ni) {
        float v = colpart[ni];
        v += __shfl_xor(v, 16, 64);   // reduce across the 4 quads (frag rows)
        v += __shfl_xor(v, 32, 64);
        if (quad == 0)
          colscratch[((jtile * 32 + dm1) * 2 + wm) * 128 + wn * 64 + ni * 16 + l16] = v;
      }
    }
    __syncthreads();   // drains stage(q+1); frees Blds[q&1] for stage(q+2)
  }
#undef STAGE_B

  // ---- row partials: shfl over the 16 col-lanes; wn-halves to SEPARATE slots
  // (both wn waves cover the same rows — separate slots, no merge, no race) ----
  #pragma unroll
  for (int i = 0; i < 16; ++i) {
    float v = rowpart[i];
    v += __shfl_xor(v, 1, 64);
    v += __shfl_xor(v, 2, 64);
    v += __shfl_xor(v, 4, 64);
    v += __shfl_xor(v, 8, 64);
    rowpart[i] = v;
  }
  if (l16 == 0) {
    #pragma unroll
    for (int mi = 0; mi < 4; ++mi)
      #pragma unroll
      for (int r = 0; r < 4; ++r)
        rowscratch[((itile * 16 + chunk) * 2 + wn) * 128 + wm * 64 + mi * 16 + quad * 4 + r]
            = rowpart[mi * 4 + r];
  }
}

// ---------------- Kernel C: gather partials per row, logf, add partial loss -------------
// Grid 64 blocks: block j handles rows [j*128,+128) and pos[j*64,+64).
// out pre-set to 0 by normalize (exp fold); each block atomicAdds its partial.
__global__ __launch_bounds__(256) void reduce_kernel(
    const float* __restrict__ rowscratch, const float* __restrict__ colscratch,
    const float* __restrict__ pos, float* __restrict__ out) {
  const int j = blockIdx.x;
  const int tid = threadIdx.x;
  float v = 0.0f;
  if (tid < 128) {
    float s = 0.0f;
    #pragma unroll
    for (int c = 0; c < 16; ++c)
      #pragma unroll
      for (int w = 0; w < 2; ++w)
        s += rowscratch[((j * 16 + c) * 2 + w) * 128 + tid];
    const int ns = (j < 32) ? 31 : 32;   // j<32: the d=32 pair arrived via rowscratch side
    for (int si = 0; si < ns; ++si)
      #pragma unroll
      for (int w = 0; w < 2; ++w)
        s += colscratch[((j * 32 + si) * 2 + w) * 128 + tid];
    v = logf(s) * (1.0f / (float)TWO_N);
  } else if (tid < 192) {
    v = -pos[j * 64 + (tid - 128)] * (INV_T / (float)N_ROWS);
  }
  #pragma unroll
  for (int m = 1; m < 64; m <<= 1) v += __shfl_xor(v, m, 64);
  __shared__ float red[4];
  if ((tid & 63) == 0) red[tid >> 6] = v;
  __syncthreads();
  if (tid == 0) atomicAdd(out, red[0] + red[1] + red[2] + red[3]);
}

extern "C" void kernel_launch(void* const* d_in, const int* in_sizes, int n_in,
                              void* d_out, int out_size, void* d_ws, size_t ws_size,
                              hipStream_t stream) {
  const float* z1 = (const float*)d_in[0];
  const float* z2 = (const float*)d_in[1];
  char* ws = (char*)d_ws;
  unsigned char* reps = (unsigned char*)ws;                // 8192*256 = 2 MB fp8
  size_t off = (size_t)TWO_N * ZDIM;
  float* pos = (float*)(ws + off);        off += N_ROWS * 4;             // 16 KB
  float* rowscratch = (float*)(ws + off); off += 64 * 16 * 2 * 128 * 4;  // 1 MB
  float* colscratch = (float*)(ws + off); off += 64 * 32 * 2 * 128 * 4;  // 2 MB

  normalize_kernel<<<1024, 256, 0, stream>>>(z1, z2, reps, pos, (float*)d_out);
  simsum_kernel<<<dim3(64, 16), 256, 0, stream>>>(reps, rowscratch, colscratch);
  reduce_kernel<<<64, 256, 0, stream>>>(rowscratch, colscratch, pos, (float*)d_out);
}